// Round 13
// baseline (281.461 us; speedup 1.0000x reference)
//
#include <hip/hip_runtime.h>

// LSTM-GCN single step from (H=0, C=0).
// Collapsed math: Fg gate dead (C_prev=0), cheb(H,..)=bh, peephole wc[0],wc[1] dead.
//
// R17: R16's nt-loads were a null (FETCH 84->86MB, 51.8->49.7us) -- gather sits
// at a latency x MSHR wall (~19 cy/record/CU), not an L2-pollution wall. The
// remaining attackable block is PIPELINE overhead: 9 serialized launches with
// ~45-60us of gaps/tails + a 25.6MB tx1 round-trip that exists only because
// gather and gates are separate. Fix: (1) fuse gather+gates (half-wave gathers
// its 8 nodes straight into the LDS ts tile, one barrier, gates math from LDS;
// kills tx1 traffic, one launch, overlaps gates VALU under gather latency);
// (2) delete scan3 (consumers apply the g_blk block-offset themselves).
// 9 launches -> 7.

#define FDIM 32
#define MAX_N 100000
#define MAX_E 1600000
#define CBSH 8                                // 256 nodes per coarse bucket
#define CB 256
#define MAX_NB ((MAX_N + CB - 1) / CB)        // 391 buckets max
#define NBLK 512                              // blocks in each edge pass
#define SCAN_TILE 2048                        // elements per scan block (256 thr x 8)
#define GNB 64                                // nodes per fused gather+gates block
#define PERBLK 3136                           // staged records per block (>= 3128)

typedef int   iv4 __attribute__((ext_vector_type(4)));
typedef float fv4 __attribute__((ext_vector_type(4)));
__device__ __forceinline__ iv4 nt_i4(const int* p)   { return __builtin_nontemporal_load((const iv4*)p); }
__device__ __forceinline__ fv4 nt_f4(const float* p) { return __builtin_nontemporal_load((const fv4*)p); }

__device__ float g_deg[MAX_N];                    // dinv (written by deg_sum)
__device__ int   g_part2[2 * MAX_NB * NBLK + 1];  // [dst bins | src bins] counts->offsets
__device__ int   g_blk[1024];                     // scan block sums (exclusive-scanned)
__device__ uint2 g_rec[MAX_E];                    // dst-sorted {src<<8|dst_loc, w}
__device__ uint2 g_srec[MAX_E];                   // src-sorted {src_loc, w}
__device__ int   g_row[MAX_N + 1];                // per-node CSR row starts
__device__ __attribute__((aligned(16))) int   g_src2[MAX_E];   // CSR src, node-sorted
__device__ __attribute__((aligned(16))) float g_nrm2[MAX_E];   // CSR nrm, node-sorted

// scan3 deleted: full scanned value = partial in g_part2 + its tile's block offset
__device__ __forceinline__ int scanned(int idx) {
    return g_part2[idx] + g_blk[idx >> 11];       // SCAN_TILE == 2048
}

// One edge pass, NO global atomics: dual LDS histograms of dst>>8 and src>>8,
// flushed non-atomically to g_part2[bin*NBLK + block]. Edge reads int4.
__global__ __launch_bounds__(256) void hist2_kernel(const int* __restrict__ ei,
                                                    int E, int n_nodes, int nbuck,
                                                    int per_blk) {
    __shared__ int hd[MAX_NB];
    __shared__ int hs[MAX_NB];
    for (int i = threadIdx.x; i < nbuck; i += 256) { hd[i] = 0; hs[i] = 0; }
    __syncthreads();
    int start = blockIdx.x * per_blk;            // per_blk % 4 == 0 -> aligned
    int end = start + per_blk;
    if (end > E) end = E;
    for (int base = start; base < end; base += 1024) {
        int e = base + threadIdx.x * 4;
        if (e + 4 <= end) {
            int4 s4 = *(const int4*)(ei + e);
            int4 d4 = *(const int4*)(ei + E + e);
#define H2(S, D) if ((unsigned)(S) < (unsigned)n_nodes && (unsigned)(D) < (unsigned)n_nodes) { \
                atomicAdd(&hd[(D) >> CBSH], 1); atomicAdd(&hs[(S) >> CBSH], 1); }
            H2(s4.x, d4.x) H2(s4.y, d4.y) H2(s4.z, d4.z) H2(s4.w, d4.w)
#undef H2
        } else if (e < end) {
            for (int q = e; q < end; ++q) {
                int s = ei[q], d = ei[E + q];
                if ((unsigned)s >= (unsigned)n_nodes || (unsigned)d >= (unsigned)n_nodes)
                    continue;
                atomicAdd(&hd[d >> CBSH], 1);
                atomicAdd(&hs[s >> CBSH], 1);
            }
        }
    }
    __syncthreads();
    for (int i = threadIdx.x; i < nbuck; i += 256) {
        g_part2[i * NBLK + blockIdx.x] = hd[i];
        g_part2[(nbuck + i) * NBLK + blockIdx.x] = hs[i];
    }
    if (blockIdx.x == 0 && threadIdx.x == 0)
        g_part2[2 * nbuck * NBLK] = 0;        // scan sentinel
}

// --- exclusive scan over g_part2[0..n): scan1 (per-tile) + scan2 (block sums).
// No scan3: consumers use scanned() to add the tile offset. ---
__global__ __launch_bounds__(256) void scan1_kernel(int n) {
    __shared__ int sh[256];
    int tid = threadIdx.x;
    int base = blockIdx.x * SCAN_TILE + tid * 8;
    int v[8];
#pragma unroll
    for (int i = 0; i < 8; ++i) v[i] = (base + i < n) ? g_part2[base + i] : 0;
    int tsum = 0;
#pragma unroll
    for (int i = 0; i < 8; ++i) tsum += v[i];
    sh[tid] = tsum;
    __syncthreads();
    for (int off = 1; off < 256; off <<= 1) {
        int t = (tid >= off) ? sh[tid - off] : 0;
        __syncthreads();
        sh[tid] += t;
        __syncthreads();
    }
    if (tid == 255) g_blk[blockIdx.x] = sh[255];
    int run = sh[tid] - tsum;   // exclusive offset within block
#pragma unroll
    for (int i = 0; i < 8; ++i) {
        if (base + i < n) g_part2[base + i] = run;
        run += v[i];
    }
}

__global__ __launch_bounds__(256) void scan2_kernel(int nb) {   // nb <= 1024
    __shared__ int sh[256];
    int tid = threadIdx.x;
    int base = tid * 4;
    int v[4];
#pragma unroll
    for (int i = 0; i < 4; ++i) v[i] = (base + i < nb) ? g_blk[base + i] : 0;
    int tsum = v[0] + v[1] + v[2] + v[3];
    sh[tid] = tsum;
    __syncthreads();
    for (int off = 1; off < 256; off <<= 1) {
        int t = (tid >= off) ? sh[tid - off] : 0;
        __syncthreads();
        sh[tid] += t;
        __syncthreads();
    }
    int run = sh[tid] - tsum;
#pragma unroll
    for (int i = 0; i < 4; ++i) {
        if (base + i < nb) g_blk[base + i] = run;
        run += v[i];
    }
}

// Two phases (dst records into g_rec, src records into g_srec). Per phase:
// counts/bases from the scanned matrix (via scanned()), 512-wide LDS
// Hillis-Steele for local run bases, cursor-scatter into staged LDS +
// per-record global position, then coalesced burst write-out.
__global__ __launch_bounds__(256) void scatter_burst_kernel(const int* __restrict__ ei,
                                                            const float* __restrict__ w,
                                                            int E, int n_nodes, int nbuck,
                                                            int per_blk) {
    __shared__ int   cnt[512];
    __shared__ int   sc[512];
    __shared__ int   gb[MAX_NB];
    __shared__ int   cur[MAX_NB];
    __shared__ uint2 staged[PERBLK];
    __shared__ int   gpos[PERBLK];
    int tid = threadIdx.x;
    int blk = blockIdx.x;
    int start = blk * per_blk;
    int end = start + per_blk;
    if (end > E) end = E;

    for (int phase = 0; phase < 2; ++phase) {
        cnt[tid] = 0; cnt[tid + 256] = 0;
        __syncthreads();
        for (int i = tid; i < nbuck; i += 256) {
            int flat = (phase * nbuck + i) * NBLK + blk;
            int g0 = scanned(flat);
            int g1 = scanned(flat + 1);            // flat successor = run end
            gb[i] = g0 - phase * E;                // src space is [E,2E)
            cnt[i] = g1 - g0;
        }
        __syncthreads();
        sc[tid] = cnt[tid]; sc[tid + 256] = cnt[tid + 256];
        __syncthreads();
        for (int off = 1; off < 512; off <<= 1) {  // inclusive scan, 512 wide
            int v0 = (tid >= off) ? sc[tid - off] : 0;
            int v1 = sc[tid + 256 - off];          // tid+256 >= off always
            __syncthreads();
            sc[tid] += v0; sc[tid + 256] += v1;
            __syncthreads();
        }
        for (int i = tid; i < nbuck; i += 256) cur[i] = sc[i] - cnt[i];
        __syncthreads();
#define SB1(S, D, W)                                                            \
        {   int s = (S), d = (D);                                               \
            if ((unsigned)s < (unsigned)n_nodes && (unsigned)d < (unsigned)n_nodes) { \
                int key = phase ? s : d;                                        \
                int bin = key >> CBSH;                                          \
                float w0 = (s == d) ? 0.f : (W);                                \
                unsigned pay = phase ? (unsigned)(s & (CB - 1))                 \
                    : (((unsigned)s << CBSH) | (unsigned)(d & (CB - 1)));       \
                int p = atomicAdd(&cur[bin], 1);                                \
                staged[p] = make_uint2(pay, __float_as_uint(w0));               \
                gpos[p] = gb[bin] + (p - (sc[bin] - cnt[bin]));                 \
            } }
        for (int base = start; base < end; base += 1024) {
            int e = base + tid * 4;
            if (e + 4 <= end) {
                iv4 s4 = nt_i4(ei + e);
                iv4 d4 = nt_i4(ei + E + e);
                fv4 w4 = nt_f4(w + e);
                SB1(s4[0], d4[0], w4[0]) SB1(s4[1], d4[1], w4[1])
                SB1(s4[2], d4[2], w4[2]) SB1(s4[3], d4[3], w4[3])
            } else if (e < end) {
                for (int q = e; q < end; ++q) SB1(ei[q], ei[E + q], w[q])
            }
        }
#undef SB1
        __syncthreads();
        int tot = sc[511];                         // valid records in this chunk
        if (phase == 0) {
            for (int t = tid; t < tot; t += 256) g_rec[gpos[t]] = staged[t];
        } else {
            for (int t = tid; t < tot; t += 256) g_srec[gpos[t]] = staged[t];
        }
        __syncthreads();
    }
}

// One block per src bucket (256 nodes): LDS f32 accumulate w per local node,
// then write dinv = rsqrt(deg) directly. No global atomics.
__global__ __launch_bounds__(256) void deg_sum_kernel(int E, int n_nodes, int nbuck) {
    __shared__ float ldeg[CB];
    int b = blockIdx.x;
    int rs = scanned((nbuck + b) * NBLK) - E;
    int re = scanned((nbuck + b + 1) * NBLK) - E;   // b==nbuck-1 hits sentinel (2E)
    ldeg[threadIdx.x] = 0.f;
    __syncthreads();
    for (int i = rs + threadIdx.x; i < re; i += 256) {
        uint2 r = g_srec[i];
        atomicAdd(&ldeg[r.x], __uint_as_float(r.y));   // LDS atomic
    }
    __syncthreads();
    int node = (b << CBSH) + threadIdx.x;
    if (node < n_nodes) {
        float dg = ldeg[threadIdx.x];
        g_deg[node] = (dg > 0.f) ? rsqrtf(dg) : 0.f;
    }
}

// One block per dst bucket (256 nodes, ~4096 records): count local nodes (LDS),
// 4-wave hierarchical exclusive scan -> absolute g_row, then reorder records
// into per-node CSR (g_src2/g_nrm2), computing nrm = -dinv[s]*w*dinv[d] on the
// fly (dinv is 400 KB -> L2-resident; bucket-side dinv staged in LDS).
__global__ __launch_bounds__(256) void fine_sort_kernel(int E, int n_nodes, int nbuck) {
    __shared__ int cnt[CB];
    __shared__ int cur[CB];
    __shared__ float dv[CB];
    __shared__ int wsum[4];
    int b = blockIdx.x;
    int rs = scanned(b * NBLK);
    int re = scanned((b + 1) * NBLK);   // b==nbuck-1 hits first src bin (= E)
    {
        int tid = threadIdx.x;
        cnt[tid] = 0;
        int node = (b << CBSH) + tid;
        dv[tid] = (node < n_nodes) ? g_deg[node] : 0.f;
    }
    __syncthreads();
    for (int i = rs + threadIdx.x; i < re; i += 256)
        atomicAdd(&cnt[g_rec[i].x & (CB - 1)], 1);
    __syncthreads();
    {
        int tid = threadIdx.x;
        int lane = tid & 63;
        int wave = tid >> 6;
        int v = cnt[tid];
        int inc = v;
#pragma unroll
        for (int off = 1; off < 64; off <<= 1) {
            int t = __shfl_up(inc, off, 64);
            if (lane >= off) inc += t;
        }
        if (lane == 63) wsum[wave] = inc;
        __syncthreads();
        int wo = 0;
#pragma unroll
        for (int ww = 0; ww < 4; ++ww) wo += (ww < wave) ? wsum[ww] : 0;
        int start = rs + wo + (inc - v);   // exclusive
        cur[tid] = start;
        int node = (b << CBSH) + tid;
        if (node < n_nodes) g_row[node] = start;
    }
    if (b == nbuck - 1 && threadIdx.x == 0) g_row[n_nodes] = re;
    __syncthreads();
    for (int i = rs + threadIdx.x; i < re; i += 256) {
        uint2 r = g_rec[i];
        int s = (int)(r.x >> CBSH);
        int loc = r.x & (CB - 1);
        float nrm = -g_deg[s] * __uint_as_float(r.y) * dv[loc];
        int pos = atomicAdd(&cur[loc], 1);   // LDS atomic
        g_src2[pos] = s;
        g_nrm2[pos] = nrm;
    }
}

// FUSED gather + gates: 64 nodes per 256-thread block (grid 1563).
// Phase 1 (gather): half-wave hh gathers its own 8 nodes (register acc, CSR nt
// loads, 8-deep unroll) and writes results straight into the LDS ts tile --
// no tx1 global round-trip. Phase 2 (gates): one barrier, then the R15 gates
// math reads Ws/xs/ts from LDS. Co-resident blocks overlap phase-2 VALU with
// phase-1 memory latency (4 blocks/CU, 32 waves/CU).
__global__ __launch_bounds__(256, 4) void gather_gates_kernel(
    const float* __restrict__ x,
    const float* __restrict__ Wx, const float* __restrict__ bx,
    const float* __restrict__ bh, const float* __restrict__ wc,
    const float* __restrict__ bg, const float* __restrict__ lin_w,
    const float* __restrict__ lin_b, float* __restrict__ out, int n_nodes) {
    __shared__ float Ws[3 * 2048];      // gates {i,c,o} x K=2 x 32x32 = 24 KB
    __shared__ float xs[GNB * FDIM];    // 8 KB
    __shared__ float ts[GNB * FDIM];    // 8 KB

    for (int idx = threadIdx.x; idx < 512; idx += 256) {
        *(float4*)&Ws[idx * 4]        = *(const float4*)&Wx[0 * 2048 + idx * 4];
        *(float4*)&Ws[2048 + idx * 4] = *(const float4*)&Wx[2 * 2048 + idx * 4];
        *(float4*)&Ws[4096 + idx * 4] = *(const float4*)&Wx[3 * 2048 + idx * 4];
    }
    int node0 = blockIdx.x * GNB;
    for (int t = threadIdx.x; t < GNB * FDIM / 4; t += 256) {
        int q = t * 4;
        int n = node0 + (q >> 5);
        float4 xv = make_float4(0.f, 0.f, 0.f, 0.f);
        if (n < n_nodes) xv = *(const float4*)&x[n * FDIM + (q & 31)];
        *(float4*)&xs[q] = xv;
    }

    int hh = threadIdx.x >> 5;          // half-wave id 0..7 = node group
    int f  = threadIdx.x & 31;
    // Phase 1: gather 8 nodes (this half-wave's own ts rows; no cross-wave dep)
    for (int m = 0; m < 8; ++m) {
        int node = node0 + hh * 8 + m;
        if (node >= n_nodes) break;
        int i = g_row[node];
        int end = g_row[node + 1];
        float acc = 0.f, accB = 0.f;
        while (i < end && (i & 3)) {    // peel to 16B alignment
            acc += g_nrm2[i] * x[g_src2[i] * FDIM + f];
            ++i;
        }
        for (; i + 8 <= end; i += 8) {
            iv4 sa = nt_i4(g_src2 + i);
            iv4 sb = nt_i4(g_src2 + i + 4);
            fv4 na = nt_f4(g_nrm2 + i);
            fv4 nb = nt_f4(g_nrm2 + i + 4);
            float xa0 = x[sa[0] * FDIM + f], xa1 = x[sa[1] * FDIM + f];
            float xa2 = x[sa[2] * FDIM + f], xa3 = x[sa[3] * FDIM + f];
            float xb0 = x[sb[0] * FDIM + f], xb1 = x[sb[1] * FDIM + f];
            float xb2 = x[sb[2] * FDIM + f], xb3 = x[sb[3] * FDIM + f];
            acc  += na[0] * xa0 + na[1] * xa1 + na[2] * xa2 + na[3] * xa3;
            accB += nb[0] * xb0 + nb[1] * xb1 + nb[2] * xb2 + nb[3] * xb3;
        }
        for (; i + 4 <= end; i += 4) {
            iv4 s4 = nt_i4(g_src2 + i);
            fv4 n4 = nt_f4(g_nrm2 + i);
            acc += n4[0] * x[s4[0] * FDIM + f] + n4[1] * x[s4[1] * FDIM + f]
                 + n4[2] * x[s4[2] * FDIM + f] + n4[3] * x[s4[3] * FDIM + f];
        }
        for (; i < end; ++i) acc += g_nrm2[i] * x[g_src2[i] * FDIM + f];
        ts[(hh * 8 + m) * FDIM + f] = acc + accB;
    }
    __syncthreads();

    // Phase 2: gates (identical math to R15's gates64, inputs already in LDS)
    int j   = threadIdx.x & 31;
    int grp = threadIdx.x >> 5;         // 0..7, handles nodes grp*8 .. grp*8+7

    float ai0=0.f,ai1=0.f,ai2=0.f,ai3=0.f,ai4=0.f,ai5=0.f,ai6=0.f,ai7=0.f;
    float ac0=0.f,ac1=0.f,ac2=0.f,ac3=0.f,ac4=0.f,ac5=0.f,ac6=0.f,ac7=0.f;
    float ao0=0.f,ao1=0.f,ao2=0.f,ao3=0.f,ao4=0.f,ao5=0.f,ao6=0.f,ao7=0.f;
    const float* xr = &xs[(grp * 8) * FDIM];
    const float* tr = &ts[(grp * 8) * FDIM];
    for (int k4 = 0; k4 < 32; k4 += 4) {
        float4 xv0 = *(const float4*)(xr + 0 * FDIM + k4);
        float4 xv1 = *(const float4*)(xr + 1 * FDIM + k4);
        float4 xv2 = *(const float4*)(xr + 2 * FDIM + k4);
        float4 xv3 = *(const float4*)(xr + 3 * FDIM + k4);
        float4 xv4 = *(const float4*)(xr + 4 * FDIM + k4);
        float4 xv5 = *(const float4*)(xr + 5 * FDIM + k4);
        float4 xv6 = *(const float4*)(xr + 6 * FDIM + k4);
        float4 xv7 = *(const float4*)(xr + 7 * FDIM + k4);
        float4 tv0 = *(const float4*)(tr + 0 * FDIM + k4);
        float4 tv1 = *(const float4*)(tr + 1 * FDIM + k4);
        float4 tv2 = *(const float4*)(tr + 2 * FDIM + k4);
        float4 tv3 = *(const float4*)(tr + 3 * FDIM + k4);
        float4 tv4 = *(const float4*)(tr + 4 * FDIM + k4);
        float4 tv5 = *(const float4*)(tr + 5 * FDIM + k4);
        float4 tv6 = *(const float4*)(tr + 6 * FDIM + k4);
        float4 tv7 = *(const float4*)(tr + 7 * FDIM + k4);
#define KSTEP(kc, COMP)                                        \
        {   int o0 = (k4 + kc) * 32 + j;                       \
            float wi0 = Ws[o0],        wi1 = Ws[1024 + o0];    \
            float wg0 = Ws[2048 + o0], wg1 = Ws[3072 + o0];    \
            float wo0 = Ws[4096 + o0], wo1 = Ws[5120 + o0];    \
            ai0 += xv0.COMP * wi0 + tv0.COMP * wi1;            \
            ac0 += xv0.COMP * wg0 + tv0.COMP * wg1;            \
            ao0 += xv0.COMP * wo0 + tv0.COMP * wo1;            \
            ai1 += xv1.COMP * wi0 + tv1.COMP * wi1;            \
            ac1 += xv1.COMP * wg0 + tv1.COMP * wg1;            \
            ao1 += xv1.COMP * wo0 + tv1.COMP * wo1;            \
            ai2 += xv2.COMP * wi0 + tv2.COMP * wi1;            \
            ac2 += xv2.COMP * wg0 + tv2.COMP * wg1;            \
            ao2 += xv2.COMP * wo0 + tv2.COMP * wo1;            \
            ai3 += xv3.COMP * wi0 + tv3.COMP * wi1;            \
            ac3 += xv3.COMP * wg0 + tv3.COMP * wg1;            \
            ao3 += xv3.COMP * wo0 + tv3.COMP * wo1;            \
            ai4 += xv4.COMP * wi0 + tv4.COMP * wi1;            \
            ac4 += xv4.COMP * wg0 + tv4.COMP * wg1;            \
            ao4 += xv4.COMP * wo0 + tv4.COMP * wo1;            \
            ai5 += xv5.COMP * wi0 + tv5.COMP * wi1;            \
            ac5 += xv5.COMP * wg0 + tv5.COMP * wg1;            \
            ao5 += xv5.COMP * wo0 + tv5.COMP * wo1;            \
            ai6 += xv6.COMP * wi0 + tv6.COMP * wi1;            \
            ac6 += xv6.COMP * wg0 + tv6.COMP * wg1;            \
            ao6 += xv6.COMP * wo0 + tv6.COMP * wo1;            \
            ai7 += xv7.COMP * wi0 + tv7.COMP * wi1;            \
            ac7 += xv7.COMP * wg0 + tv7.COMP * wg1;            \
            ao7 += xv7.COMP * wo0 + tv7.COMP * wo1;            \
        }
        KSTEP(0, x) KSTEP(1, y) KSTEP(2, z) KSTEP(3, w)
#undef KSTEP
    }

    float bi = bx[0 * 32 + j] + bh[0 * 32 + j] + bg[0 * 32 + j];
    float bc = bx[2 * 32 + j] + bh[2 * 32 + j] + bg[2 * 32 + j];
    float bo = bx[3 * 32 + j] + bh[3 * 32 + j] + bg[3 * 32 + j];
    float wcp = wc[2 * 32 + j];
    float lwj = lin_w[j];
    float lb0 = lin_b[0];

#define GOUT(m, AI, AC, AO)                                            \
    {   int n = node0 + grp * 8 + m;                                   \
        float I = 1.f / (1.f + __expf(-(AI + bi)));                    \
        float T = tanhf(AC + bc);                                      \
        float C = I * T;                                               \
        float O = 1.f / (1.f + __expf(-(AO + bo + wcp * C)));          \
        float H = O * tanhf(C);                                        \
        float r = fmaxf(H, 0.f) * lwj;                                 \
        _Pragma("unroll")                                              \
        for (int mm = 16; mm > 0; mm >>= 1) r += __shfl_xor(r, mm, 32);\
        if (j == 0 && n < n_nodes) out[n] = r + lb0; }
    GOUT(0, ai0, ac0, ao0) GOUT(1, ai1, ac1, ao1)
    GOUT(2, ai2, ac2, ao2) GOUT(3, ai3, ac3, ao3)
    GOUT(4, ai4, ac4, ao4) GOUT(5, ai5, ac5, ao5)
    GOUT(6, ai6, ac6, ao6) GOUT(7, ai7, ac7, ao7)
#undef GOUT
}

extern "C" void kernel_launch(void* const* d_in, const int* in_sizes, int n_in,
                              void* d_out, int out_size, void* d_ws, size_t ws_size,
                              hipStream_t stream) {
    const float* x     = (const float*)d_in[0];
    const int*   ei    = (const int*)d_in[1];      // int32 on device
    const float* w     = (const float*)d_in[2];
    const float* Wx    = (const float*)d_in[3];
    const float* bx    = (const float*)d_in[4];
    // d_in[5] = Wh: unused (H=0)
    const float* bh    = (const float*)d_in[6];
    const float* wc    = (const float*)d_in[7];
    const float* bg    = (const float*)d_in[8];
    const float* lin_w = (const float*)d_in[9];
    const float* lin_b = (const float*)d_in[10];
    float*       out   = (float*)d_out;

    int n_nodes = in_sizes[0] / FDIM;
    if (n_nodes > MAX_N) n_nodes = MAX_N;
    int E = in_sizes[2];
    if (E > MAX_E) E = MAX_E;

    int nbuck   = (n_nodes + CB - 1) >> CBSH;            // 391 for N=100k
    int per_blk = (((E + NBLK - 1) / NBLK) + 3) & ~3;    // 3128, x4-aligned ranges
    int n_scan  = 2 * nbuck * NBLK + 1;                  // 400385
    int nb_scan = (n_scan + SCAN_TILE - 1) / SCAN_TILE;  // 196 (<= 1024 for scan2)

    hist2_kernel<<<NBLK, 256, 0, stream>>>(ei, E, n_nodes, nbuck, per_blk);
    scan1_kernel<<<nb_scan, 256, 0, stream>>>(n_scan);
    scan2_kernel<<<1, 256, 0, stream>>>(nb_scan);
    scatter_burst_kernel<<<NBLK, 256, 0, stream>>>(ei, w, E, n_nodes, nbuck, per_blk);
    deg_sum_kernel<<<nbuck, 256, 0, stream>>>(E, n_nodes, nbuck);
    fine_sort_kernel<<<nbuck, 256, 0, stream>>>(E, n_nodes, nbuck);
    gather_gates_kernel<<<(n_nodes + GNB - 1) / GNB, 256, 0, stream>>>(
        x, Wx, bx, bh, wc, bg, lin_w, lin_b, out, n_nodes);
}

// Round 14
// 264.044 us; speedup vs baseline: 1.0660x; 1.0660x over previous
//
#include <hip/hip_runtime.h>

// LSTM-GCN single step from (H=0, C=0).
// Collapsed math: Fg gate dead (C_prev=0), cheb(H,..)=bh, peephole wc[0],wc[1] dead.
//
// R18: R17's gather+gates fusion REGRESSED (254->281; fused kernel 123.9us at
// 32.5% occupancy -- the 40KB gates LDS halved the latency-bound gather's
// resident waves; tx1 saving was ~5us vs ~35us occupancy loss). Revert to
// separate gather+gates (R16 versions), keep the scan3 deletion (scanned()).
// Forward move: ONE-PASS scatter -- both axes' cursors set up first (counts
// from the scanned matrix, two 512-wide scans), then a SINGLE edge pass stages
// dst+src records in LDS, then two coalesced bursts. NBLK 512->1024 (staging
// halves to fit ~51KB LDS; doubles edge-pass parallelism). Saves one 19.2MB
// edge re-read + half the scan overhead. 8 dispatches.

#define FDIM 32
#define MAX_N 100000
#define MAX_E 1600000
#define CBSH 8                                // 256 nodes per coarse bucket
#define CB 256
#define MAX_NB ((MAX_N + CB - 1) / CB)        // 391 buckets max
#define NBLK 1024                             // blocks in each edge pass
#define SCAN_TILE 2048                        // elements per scan block (256 thr x 8)
#define GNB 64                                // nodes per gates block
#define PERBLK 1568                           // staged records per block (>= 1564)

typedef int   iv4 __attribute__((ext_vector_type(4)));
typedef float fv4 __attribute__((ext_vector_type(4)));
__device__ __forceinline__ iv4 nt_i4(const int* p)   { return __builtin_nontemporal_load((const iv4*)p); }
__device__ __forceinline__ fv4 nt_f4(const float* p) { return __builtin_nontemporal_load((const fv4*)p); }

__device__ float g_deg[MAX_N];                    // dinv (written by deg_sum)
__device__ int   g_part2[2 * MAX_NB * NBLK + 1];  // [dst bins | src bins] counts->offsets
__device__ int   g_blk[1024];                     // scan tile sums (exclusive-scanned)
__device__ uint2 g_rec[MAX_E];                    // dst-sorted {src<<8|dst_loc, w}
__device__ uint2 g_srec[MAX_E];                   // src-sorted {src_loc, w}
__device__ int   g_row[MAX_N + 1];                // per-node CSR row starts
__device__ __attribute__((aligned(16))) int   g_src2[MAX_E];   // CSR src, node-sorted
__device__ __attribute__((aligned(16))) float g_nrm2[MAX_E];   // CSR nrm, node-sorted
__device__ float g_tx1[MAX_N * FDIM];             // L_hat @ x

// scan3 deleted: full scanned value = partial in g_part2 + its tile's offset
__device__ __forceinline__ int scanned(int idx) {
    return g_part2[idx] + g_blk[idx >> 11];       // SCAN_TILE == 2048
}

// One edge pass, NO global atomics: dual LDS histograms of dst>>8 and src>>8,
// flushed non-atomically to g_part2[bin*NBLK + block]. Edge reads int4.
__global__ __launch_bounds__(256) void hist2_kernel(const int* __restrict__ ei,
                                                    int E, int n_nodes, int nbuck,
                                                    int per_blk) {
    __shared__ int hd[MAX_NB];
    __shared__ int hs[MAX_NB];
    for (int i = threadIdx.x; i < nbuck; i += 256) { hd[i] = 0; hs[i] = 0; }
    __syncthreads();
    int start = blockIdx.x * per_blk;            // per_blk % 4 == 0 -> aligned
    int end = start + per_blk;
    if (end > E) end = E;
    for (int base = start; base < end; base += 1024) {
        int e = base + threadIdx.x * 4;
        if (e + 4 <= end) {
            int4 s4 = *(const int4*)(ei + e);
            int4 d4 = *(const int4*)(ei + E + e);
#define H2(S, D) if ((unsigned)(S) < (unsigned)n_nodes && (unsigned)(D) < (unsigned)n_nodes) { \
                atomicAdd(&hd[(D) >> CBSH], 1); atomicAdd(&hs[(S) >> CBSH], 1); }
            H2(s4.x, d4.x) H2(s4.y, d4.y) H2(s4.z, d4.z) H2(s4.w, d4.w)
#undef H2
        } else if (e < end) {
            for (int q = e; q < end; ++q) {
                int s = ei[q], d = ei[E + q];
                if ((unsigned)s >= (unsigned)n_nodes || (unsigned)d >= (unsigned)n_nodes)
                    continue;
                atomicAdd(&hd[d >> CBSH], 1);
                atomicAdd(&hs[s >> CBSH], 1);
            }
        }
    }
    __syncthreads();
    for (int i = threadIdx.x; i < nbuck; i += 256) {
        g_part2[i * NBLK + blockIdx.x] = hd[i];
        g_part2[(nbuck + i) * NBLK + blockIdx.x] = hs[i];
    }
    if (blockIdx.x == 0 && threadIdx.x == 0)
        g_part2[2 * nbuck * NBLK] = 0;        // scan sentinel
}

// --- exclusive scan over g_part2[0..n): scan1 (per-tile) + scan2 (tile sums).
// No scan3: consumers use scanned(). n ~ 800K -> 392 tiles. ---
__global__ __launch_bounds__(256) void scan1_kernel(int n) {
    __shared__ int sh[256];
    int tid = threadIdx.x;
    int base = blockIdx.x * SCAN_TILE + tid * 8;
    int v[8];
#pragma unroll
    for (int i = 0; i < 8; ++i) v[i] = (base + i < n) ? g_part2[base + i] : 0;
    int tsum = 0;
#pragma unroll
    for (int i = 0; i < 8; ++i) tsum += v[i];
    sh[tid] = tsum;
    __syncthreads();
    for (int off = 1; off < 256; off <<= 1) {
        int t = (tid >= off) ? sh[tid - off] : 0;
        __syncthreads();
        sh[tid] += t;
        __syncthreads();
    }
    if (tid == 255) g_blk[blockIdx.x] = sh[255];
    int run = sh[tid] - tsum;   // exclusive offset within tile
#pragma unroll
    for (int i = 0; i < 8; ++i) {
        if (base + i < n) g_part2[base + i] = run;
        run += v[i];
    }
}

__global__ __launch_bounds__(256) void scan2_kernel(int nb) {   // nb <= 1024
    __shared__ int sh[256];
    int tid = threadIdx.x;
    int base = tid * 4;
    int v[4];
#pragma unroll
    for (int i = 0; i < 4; ++i) v[i] = (base + i < nb) ? g_blk[base + i] : 0;
    int tsum = v[0] + v[1] + v[2] + v[3];
    sh[tid] = tsum;
    __syncthreads();
    for (int off = 1; off < 256; off <<= 1) {
        int t = (tid >= off) ? sh[tid - off] : 0;
        __syncthreads();
        sh[tid] += t;
        __syncthreads();
    }
    int run = sh[tid] - tsum;
#pragma unroll
    for (int i = 0; i < 4; ++i) {
        if (base + i < nb) g_blk[base + i] = run;
        run += v[i];
    }
}

// ONE-PASS scatter: set up dst AND src cursors (counts/bases from the scanned
// matrix via scanned(), two 512-wide LDS Hillis-Steele scans), then a SINGLE
// edge pass stages both record types in LDS + per-record global positions,
// then two coalesced burst write-outs. No global atomics; lines written fully.
__global__ __launch_bounds__(256) void scatter1_kernel(const int* __restrict__ ei,
                                                       const float* __restrict__ w,
                                                       int E, int n_nodes, int nbuck,
                                                       int per_blk) {
    __shared__ int   scrC[512];
    __shared__ int   scrI[512];
    __shared__ int   gbD[MAX_NB], baseD[MAX_NB], curD[MAX_NB];
    __shared__ int   gbS[MAX_NB], baseS[MAX_NB], curS[MAX_NB];
    __shared__ uint2 stagedD[PERBLK];
    __shared__ uint2 stagedS[PERBLK];
    __shared__ int   gposD[PERBLK];
    __shared__ int   gposS[PERBLK];
    __shared__ int   tot;
    int tid = threadIdx.x;
    int blk = blockIdx.x;
    int start = blk * per_blk;
    int end = start + per_blk;
    if (end > E) end = E;

    // ---- axis D setup ----
    scrC[tid] = 0; scrC[tid + 256] = 0;
    __syncthreads();
    for (int i = tid; i < nbuck; i += 256) {
        int flat = i * NBLK + blk;
        int g0 = scanned(flat), g1 = scanned(flat + 1);
        gbD[i] = g0;
        scrC[i] = g1 - g0;
    }
    __syncthreads();
    scrI[tid] = scrC[tid]; scrI[tid + 256] = scrC[tid + 256];
    __syncthreads();
    for (int off = 1; off < 512; off <<= 1) {      // inclusive scan, 512 wide
        int v0 = (tid >= off) ? scrI[tid - off] : 0;
        int v1 = scrI[tid + 256 - off];            // tid+256 >= off always
        __syncthreads();
        scrI[tid] += v0; scrI[tid + 256] += v1;
        __syncthreads();
    }
    for (int i = tid; i < nbuck; i += 256) {
        int b0 = scrI[i] - scrC[i];
        baseD[i] = b0; curD[i] = b0;
    }
    if (tid == 0) tot = scrI[511];                 // valid edges in this chunk
    __syncthreads();

    // ---- axis S setup (reuses scratch) ----
    scrC[tid] = 0; scrC[tid + 256] = 0;
    __syncthreads();
    for (int i = tid; i < nbuck; i += 256) {
        int flat = (nbuck + i) * NBLK + blk;
        int g0 = scanned(flat), g1 = scanned(flat + 1);
        gbS[i] = g0 - E;                           // src space is [E,2E)
        scrC[i] = g1 - g0;
    }
    __syncthreads();
    scrI[tid] = scrC[tid]; scrI[tid + 256] = scrC[tid + 256];
    __syncthreads();
    for (int off = 1; off < 512; off <<= 1) {
        int v0 = (tid >= off) ? scrI[tid - off] : 0;
        int v1 = scrI[tid + 256 - off];
        __syncthreads();
        scrI[tid] += v0; scrI[tid + 256] += v1;
        __syncthreads();
    }
    for (int i = tid; i < nbuck; i += 256) {
        int b0 = scrI[i] - scrC[i];
        baseS[i] = b0; curS[i] = b0;
    }
    __syncthreads();

    // ---- single edge pass: stage BOTH record types ----
#define SB1(S, D, W)                                                            \
    {   int s = (S), d = (D);                                                   \
        if ((unsigned)s < (unsigned)n_nodes && (unsigned)d < (unsigned)n_nodes) { \
            float w0 = (s == d) ? 0.f : (W);       /* self-loops: w=0 */        \
            int bD = d >> CBSH;                                                 \
            int pD = atomicAdd(&curD[bD], 1);      /* LDS cursor */             \
            stagedD[pD] = make_uint2(((unsigned)s << CBSH) | (unsigned)(d & (CB - 1)), \
                                     __float_as_uint(w0));                      \
            gposD[pD] = gbD[bD] + (pD - baseD[bD]);                             \
            int bS = s >> CBSH;                                                 \
            int pS = atomicAdd(&curS[bS], 1);                                   \
            stagedS[pS] = make_uint2((unsigned)(s & (CB - 1)), __float_as_uint(w0)); \
            gposS[pS] = gbS[bS] + (pS - baseS[bS]);                             \
        } }
    for (int base = start; base < end; base += 1024) {
        int e = base + tid * 4;
        if (e + 4 <= end) {
            iv4 s4 = nt_i4(ei + e);
            iv4 d4 = nt_i4(ei + E + e);
            fv4 w4 = nt_f4(w + e);
            SB1(s4[0], d4[0], w4[0]) SB1(s4[1], d4[1], w4[1])
            SB1(s4[2], d4[2], w4[2]) SB1(s4[3], d4[3], w4[3])
        } else if (e < end) {
            for (int q = e; q < end; ++q) SB1(ei[q], ei[E + q], w[q])
        }
    }
#undef SB1
    __syncthreads();
    // ---- coalesced bursts: every 64B line written fully, evicted once ----
    for (int t = tid; t < tot; t += 256) g_rec[gposD[t]] = stagedD[t];
    for (int t = tid; t < tot; t += 256) g_srec[gposS[t]] = stagedS[t];
}

// One block per src bucket (256 nodes): LDS f32 accumulate w per local node,
// then write dinv = rsqrt(deg) directly. No global atomics.
__global__ __launch_bounds__(256) void deg_sum_kernel(int E, int n_nodes, int nbuck) {
    __shared__ float ldeg[CB];
    int b = blockIdx.x;
    int rs = scanned((nbuck + b) * NBLK) - E;
    int re = scanned((nbuck + b + 1) * NBLK) - E;   // b==nbuck-1 hits sentinel (2E)
    ldeg[threadIdx.x] = 0.f;
    __syncthreads();
    for (int i = rs + threadIdx.x; i < re; i += 256) {
        uint2 r = g_srec[i];
        atomicAdd(&ldeg[r.x], __uint_as_float(r.y));   // LDS atomic
    }
    __syncthreads();
    int node = (b << CBSH) + threadIdx.x;
    if (node < n_nodes) {
        float dg = ldeg[threadIdx.x];
        g_deg[node] = (dg > 0.f) ? rsqrtf(dg) : 0.f;
    }
}

// One block per dst bucket (256 nodes, ~4096 records): count local nodes (LDS),
// 4-wave hierarchical exclusive scan -> absolute g_row, then reorder records
// into per-node CSR (g_src2/g_nrm2), computing nrm = -dinv[s]*w*dinv[d] on the
// fly (dinv is 400 KB -> L2-resident; bucket-side dinv staged in LDS).
__global__ __launch_bounds__(256) void fine_sort_kernel(int E, int n_nodes, int nbuck) {
    __shared__ int cnt[CB];
    __shared__ int cur[CB];
    __shared__ float dv[CB];
    __shared__ int wsum[4];
    int b = blockIdx.x;
    int rs = scanned(b * NBLK);
    int re = scanned((b + 1) * NBLK);   // b==nbuck-1 hits first src bin (= E)
    {
        int tid = threadIdx.x;
        cnt[tid] = 0;
        int node = (b << CBSH) + tid;
        dv[tid] = (node < n_nodes) ? g_deg[node] : 0.f;
    }
    __syncthreads();
    for (int i = rs + threadIdx.x; i < re; i += 256)
        atomicAdd(&cnt[g_rec[i].x & (CB - 1)], 1);
    __syncthreads();
    {
        int tid = threadIdx.x;
        int lane = tid & 63;
        int wave = tid >> 6;
        int v = cnt[tid];
        int inc = v;
#pragma unroll
        for (int off = 1; off < 64; off <<= 1) {
            int t = __shfl_up(inc, off, 64);
            if (lane >= off) inc += t;
        }
        if (lane == 63) wsum[wave] = inc;
        __syncthreads();
        int wo = 0;
#pragma unroll
        for (int ww = 0; ww < 4; ++ww) wo += (ww < wave) ? wsum[ww] : 0;
        int start = rs + wo + (inc - v);   // exclusive
        cur[tid] = start;
        int node = (b << CBSH) + tid;
        if (node < n_nodes) g_row[node] = start;
    }
    if (b == nbuck - 1 && threadIdx.x == 0) g_row[n_nodes] = re;
    __syncthreads();
    for (int i = rs + threadIdx.x; i < re; i += 256) {
        uint2 r = g_rec[i];
        int s = (int)(r.x >> CBSH);
        int loc = r.x & (CB - 1);
        float nrm = -g_deg[s] * __uint_as_float(r.y) * dv[loc];
        int pos = atomicAdd(&cur[loc], 1);   // LDS atomic
        g_src2[pos] = s;
        g_nrm2[pos] = nrm;
    }
}

// Half-wave (32 lanes = 32 features) per node, REGISTER accumulators (dual),
// CSR stream nt, 8-deep unroll; 12.5k blocks -> the latency wall needs max
// wave concurrency (this is why R17's fusion with the 40KB gates LDS lost).
__global__ __launch_bounds__(256) void gather_kernel(const float* __restrict__ x,
                                                     int n_nodes) {
    int t = blockIdx.x * blockDim.x + threadIdx.x;
    int node = t >> 5;
    int f = t & 31;
    if (node >= n_nodes) return;
    int i = g_row[node];
    int end = g_row[node + 1];
    float acc = 0.f, accB = 0.f;
    while (i < end && (i & 3)) {           // peel to 16B alignment
        acc += g_nrm2[i] * x[g_src2[i] * FDIM + f];
        ++i;
    }
    for (; i + 8 <= end; i += 8) {
        iv4 sa = nt_i4(g_src2 + i);
        iv4 sb = nt_i4(g_src2 + i + 4);
        fv4 na = nt_f4(g_nrm2 + i);
        fv4 nb = nt_f4(g_nrm2 + i + 4);
        float xa0 = x[sa[0] * FDIM + f], xa1 = x[sa[1] * FDIM + f];
        float xa2 = x[sa[2] * FDIM + f], xa3 = x[sa[3] * FDIM + f];
        float xb0 = x[sb[0] * FDIM + f], xb1 = x[sb[1] * FDIM + f];
        float xb2 = x[sb[2] * FDIM + f], xb3 = x[sb[3] * FDIM + f];
        acc  += na[0] * xa0 + na[1] * xa1 + na[2] * xa2 + na[3] * xa3;
        accB += nb[0] * xb0 + nb[1] * xb1 + nb[2] * xb2 + nb[3] * xb3;
    }
    for (; i + 4 <= end; i += 4) {
        iv4 s4 = nt_i4(g_src2 + i);
        fv4 n4 = nt_f4(g_nrm2 + i);
        acc += n4[0] * x[s4[0] * FDIM + f] + n4[1] * x[s4[1] * FDIM + f]
             + n4[2] * x[s4[2] * FDIM + f] + n4[3] * x[s4[3] * FDIM + f];
    }
    for (; i < end; ++i) acc += g_nrm2[i] * x[g_src2[i] * FDIM + f];
    g_tx1[node * FDIM + f] = acc + accB;
}

// 64 nodes per 256-thread block. Thread (grp, j) accumulates output feature j
// of gates i,c,o for 8 nodes. k processed in chunks of 4: x/t read as float4
// broadcasts (b128, conflict-free), weights b32 coalesced.
__global__ __launch_bounds__(256, 4) void gates64_kernel(
    const float* __restrict__ x,
    const float* __restrict__ Wx, const float* __restrict__ bx,
    const float* __restrict__ bh, const float* __restrict__ wc,
    const float* __restrict__ bg, const float* __restrict__ lin_w,
    const float* __restrict__ lin_b, float* __restrict__ out, int n_nodes) {
    __shared__ float Ws[3 * 2048];      // gates {i,c,o} x K=2 x 32x32 = 24 KB
    __shared__ float xs[GNB * FDIM];    // 8 KB
    __shared__ float ts[GNB * FDIM];    // 8 KB

    for (int idx = threadIdx.x; idx < 512; idx += 256) {
        *(float4*)&Ws[idx * 4]        = *(const float4*)&Wx[0 * 2048 + idx * 4];
        *(float4*)&Ws[2048 + idx * 4] = *(const float4*)&Wx[2 * 2048 + idx * 4];
        *(float4*)&Ws[4096 + idx * 4] = *(const float4*)&Wx[3 * 2048 + idx * 4];
    }
    int node0 = blockIdx.x * GNB;
    for (int t = threadIdx.x; t < GNB * FDIM / 4; t += 256) {
        int q = t * 4;
        int n = node0 + (q >> 5);
        float4 xv = make_float4(0.f, 0.f, 0.f, 0.f);
        float4 tv = make_float4(0.f, 0.f, 0.f, 0.f);
        if (n < n_nodes) {
            xv = *(const float4*)&x[n * FDIM + (q & 31)];
            tv = *(const float4*)&g_tx1[n * FDIM + (q & 31)];
        }
        *(float4*)&xs[q] = xv;
        *(float4*)&ts[q] = tv;
    }
    __syncthreads();

    int j   = threadIdx.x & 31;
    int grp = threadIdx.x >> 5;         // 0..7, handles nodes grp*8 .. grp*8+7

    float ai0=0.f,ai1=0.f,ai2=0.f,ai3=0.f,ai4=0.f,ai5=0.f,ai6=0.f,ai7=0.f;
    float ac0=0.f,ac1=0.f,ac2=0.f,ac3=0.f,ac4=0.f,ac5=0.f,ac6=0.f,ac7=0.f;
    float ao0=0.f,ao1=0.f,ao2=0.f,ao3=0.f,ao4=0.f,ao5=0.f,ao6=0.f,ao7=0.f;
    const float* xr = &xs[(grp * 8) * FDIM];
    const float* tr = &ts[(grp * 8) * FDIM];
    for (int k4 = 0; k4 < 32; k4 += 4) {
        float4 xv0 = *(const float4*)(xr + 0 * FDIM + k4);
        float4 xv1 = *(const float4*)(xr + 1 * FDIM + k4);
        float4 xv2 = *(const float4*)(xr + 2 * FDIM + k4);
        float4 xv3 = *(const float4*)(xr + 3 * FDIM + k4);
        float4 xv4 = *(const float4*)(xr + 4 * FDIM + k4);
        float4 xv5 = *(const float4*)(xr + 5 * FDIM + k4);
        float4 xv6 = *(const float4*)(xr + 6 * FDIM + k4);
        float4 xv7 = *(const float4*)(xr + 7 * FDIM + k4);
        float4 tv0 = *(const float4*)(tr + 0 * FDIM + k4);
        float4 tv1 = *(const float4*)(tr + 1 * FDIM + k4);
        float4 tv2 = *(const float4*)(tr + 2 * FDIM + k4);
        float4 tv3 = *(const float4*)(tr + 3 * FDIM + k4);
        float4 tv4 = *(const float4*)(tr + 4 * FDIM + k4);
        float4 tv5 = *(const float4*)(tr + 5 * FDIM + k4);
        float4 tv6 = *(const float4*)(tr + 6 * FDIM + k4);
        float4 tv7 = *(const float4*)(tr + 7 * FDIM + k4);
#define KSTEP(kc, COMP)                                        \
        {   int o0 = (k4 + kc) * 32 + j;                       \
            float wi0 = Ws[o0],        wi1 = Ws[1024 + o0];    \
            float wg0 = Ws[2048 + o0], wg1 = Ws[3072 + o0];    \
            float wo0 = Ws[4096 + o0], wo1 = Ws[5120 + o0];    \
            ai0 += xv0.COMP * wi0 + tv0.COMP * wi1;            \
            ac0 += xv0.COMP * wg0 + tv0.COMP * wg1;            \
            ao0 += xv0.COMP * wo0 + tv0.COMP * wo1;            \
            ai1 += xv1.COMP * wi0 + tv1.COMP * wi1;            \
            ac1 += xv1.COMP * wg0 + tv1.COMP * wg1;            \
            ao1 += xv1.COMP * wo0 + tv1.COMP * wo1;            \
            ai2 += xv2.COMP * wi0 + tv2.COMP * wi1;            \
            ac2 += xv2.COMP * wg0 + tv2.COMP * wg1;            \
            ao2 += xv2.COMP * wo0 + tv2.COMP * wo1;            \
            ai3 += xv3.COMP * wi0 + tv3.COMP * wi1;            \
            ac3 += xv3.COMP * wg0 + tv3.COMP * wg1;            \
            ao3 += xv3.COMP * wo0 + tv3.COMP * wo1;            \
            ai4 += xv4.COMP * wi0 + tv4.COMP * wi1;            \
            ac4 += xv4.COMP * wg0 + tv4.COMP * wg1;            \
            ao4 += xv4.COMP * wo0 + tv4.COMP * wo1;            \
            ai5 += xv5.COMP * wi0 + tv5.COMP * wi1;            \
            ac5 += xv5.COMP * wg0 + tv5.COMP * wg1;            \
            ao5 += xv5.COMP * wo0 + tv5.COMP * wo1;            \
            ai6 += xv6.COMP * wi0 + tv6.COMP * wi1;            \
            ac6 += xv6.COMP * wg0 + tv6.COMP * wg1;            \
            ao6 += xv6.COMP * wo0 + tv6.COMP * wo1;            \
            ai7 += xv7.COMP * wi0 + tv7.COMP * wi1;            \
            ac7 += xv7.COMP * wg0 + tv7.COMP * wg1;            \
            ao7 += xv7.COMP * wo0 + tv7.COMP * wo1;            \
        }
        KSTEP(0, x) KSTEP(1, y) KSTEP(2, z) KSTEP(3, w)
#undef KSTEP
    }

    float bi = bx[0 * 32 + j] + bh[0 * 32 + j] + bg[0 * 32 + j];
    float bc = bx[2 * 32 + j] + bh[2 * 32 + j] + bg[2 * 32 + j];
    float bo = bx[3 * 32 + j] + bh[3 * 32 + j] + bg[3 * 32 + j];
    float wcp = wc[2 * 32 + j];
    float lwj = lin_w[j];
    float lb0 = lin_b[0];

#define GOUT(m, AI, AC, AO)                                            \
    {   int n = node0 + grp * 8 + m;                                   \
        float I = 1.f / (1.f + __expf(-(AI + bi)));                    \
        float T = tanhf(AC + bc);                                      \
        float C = I * T;                                               \
        float O = 1.f / (1.f + __expf(-(AO + bo + wcp * C)));          \
        float H = O * tanhf(C);                                        \
        float r = fmaxf(H, 0.f) * lwj;                                 \
        _Pragma("unroll")                                              \
        for (int mm = 16; mm > 0; mm >>= 1) r += __shfl_xor(r, mm, 32);\
        if (j == 0 && n < n_nodes) out[n] = r + lb0; }
    GOUT(0, ai0, ac0, ao0) GOUT(1, ai1, ac1, ao1)
    GOUT(2, ai2, ac2, ao2) GOUT(3, ai3, ac3, ao3)
    GOUT(4, ai4, ac4, ao4) GOUT(5, ai5, ac5, ao5)
    GOUT(6, ai6, ac6, ao6) GOUT(7, ai7, ac7, ao7)
#undef GOUT
}

extern "C" void kernel_launch(void* const* d_in, const int* in_sizes, int n_in,
                              void* d_out, int out_size, void* d_ws, size_t ws_size,
                              hipStream_t stream) {
    const float* x     = (const float*)d_in[0];
    const int*   ei    = (const int*)d_in[1];      // int32 on device
    const float* w     = (const float*)d_in[2];
    const float* Wx    = (const float*)d_in[3];
    const float* bx    = (const float*)d_in[4];
    // d_in[5] = Wh: unused (H=0)
    const float* bh    = (const float*)d_in[6];
    const float* wc    = (const float*)d_in[7];
    const float* bg    = (const float*)d_in[8];
    const float* lin_w = (const float*)d_in[9];
    const float* lin_b = (const float*)d_in[10];
    float*       out   = (float*)d_out;

    int n_nodes = in_sizes[0] / FDIM;
    if (n_nodes > MAX_N) n_nodes = MAX_N;
    int E = in_sizes[2];
    if (E > MAX_E) E = MAX_E;

    int nbuck   = (n_nodes + CB - 1) >> CBSH;            // 391 for N=100k
    int per_blk = (((E + NBLK - 1) / NBLK) + 3) & ~3;    // 1564, x4-aligned ranges
    int n_scan  = 2 * nbuck * NBLK + 1;                  // 800769
    int nb_scan = (n_scan + SCAN_TILE - 1) / SCAN_TILE;  // 392 (<= 1024 for scan2)

    hist2_kernel<<<NBLK, 256, 0, stream>>>(ei, E, n_nodes, nbuck, per_blk);
    scan1_kernel<<<nb_scan, 256, 0, stream>>>(n_scan);
    scan2_kernel<<<1, 256, 0, stream>>>(nb_scan);
    scatter1_kernel<<<NBLK, 256, 0, stream>>>(ei, w, E, n_nodes, nbuck, per_blk);
    deg_sum_kernel<<<nbuck, 256, 0, stream>>>(E, n_nodes, nbuck);
    fine_sort_kernel<<<nbuck, 256, 0, stream>>>(E, n_nodes, nbuck);
    {
        long long tot = (long long)n_nodes * 32;
        gather_kernel<<<(int)((tot + 255) / 256), 256, 0, stream>>>(x, n_nodes);
    }
    gates64_kernel<<<(n_nodes + GNB - 1) / GNB, 256, 0, stream>>>(
        x, Wx, bx, bh, wc, bg, lin_w, lin_b, out, n_nodes);
}

// Round 15
// 248.100 us; speedup vs baseline: 1.1345x; 1.0643x over previous
//
#include <hip/hip_runtime.h>

// LSTM-GCN single step from (H=0, C=0).
// Collapsed math: Fg gate dead (C_prev=0), cheb(H,..)=bh, peephole wc[0],wc[1] dead.
//
// R19: R18's one-pass scatter regressed vs R16 (264 vs 254): 51KB LDS capped
// the edge pass at 3 blocks/CU and NBLK=1024 doubled the part2 scan. Revert to
// R16's two-pass scatter_burst @ NBLK=512 (keep scanned()). NEW lever: deg_sum
// and fine_sort ran 391 blocks x 256 thr = 19% occupancy (same starvation R10
// found in the bucket gather). Widen both to 1024 threads/block (6256 waves,
// 76% occupancy; bucket scan on first 4 waves; record loops get 4x threads).

#define FDIM 32
#define MAX_N 100000
#define MAX_E 1600000
#define CBSH 8                                // 256 nodes per coarse bucket
#define CB 256
#define MAX_NB ((MAX_N + CB - 1) / CB)        // 391 buckets max
#define NBLK 512                              // blocks in each edge pass
#define SCAN_TILE 2048                        // elements per scan block (256 thr x 8)
#define GNB 64                                // nodes per gates block
#define PERBLK 3136                           // staged records per block (>= 3128)

typedef int   iv4 __attribute__((ext_vector_type(4)));
typedef float fv4 __attribute__((ext_vector_type(4)));
__device__ __forceinline__ iv4 nt_i4(const int* p)   { return __builtin_nontemporal_load((const iv4*)p); }
__device__ __forceinline__ fv4 nt_f4(const float* p) { return __builtin_nontemporal_load((const fv4*)p); }

__device__ float g_deg[MAX_N];                    // dinv (written by deg_sum)
__device__ int   g_part2[2 * MAX_NB * NBLK + 1];  // [dst bins | src bins] counts->offsets
__device__ int   g_blk[1024];                     // scan tile sums (exclusive-scanned)
__device__ uint2 g_rec[MAX_E];                    // dst-sorted {src<<8|dst_loc, w}
__device__ uint2 g_srec[MAX_E];                   // src-sorted {src_loc, w}
__device__ int   g_row[MAX_N + 1];                // per-node CSR row starts
__device__ __attribute__((aligned(16))) int   g_src2[MAX_E];   // CSR src, node-sorted
__device__ __attribute__((aligned(16))) float g_nrm2[MAX_E];   // CSR nrm, node-sorted
__device__ float g_tx1[MAX_N * FDIM];             // L_hat @ x

// scan3 deleted: full scanned value = partial in g_part2 + its tile's offset
__device__ __forceinline__ int scanned(int idx) {
    return g_part2[idx] + g_blk[idx >> 11];       // SCAN_TILE == 2048
}

// One edge pass, NO global atomics: dual LDS histograms of dst>>8 and src>>8,
// flushed non-atomically to g_part2[bin*NBLK + block]. Edge reads int4.
__global__ __launch_bounds__(256) void hist2_kernel(const int* __restrict__ ei,
                                                    int E, int n_nodes, int nbuck,
                                                    int per_blk) {
    __shared__ int hd[MAX_NB];
    __shared__ int hs[MAX_NB];
    for (int i = threadIdx.x; i < nbuck; i += 256) { hd[i] = 0; hs[i] = 0; }
    __syncthreads();
    int start = blockIdx.x * per_blk;            // per_blk % 4 == 0 -> aligned
    int end = start + per_blk;
    if (end > E) end = E;
    for (int base = start; base < end; base += 1024) {
        int e = base + threadIdx.x * 4;
        if (e + 4 <= end) {
            int4 s4 = *(const int4*)(ei + e);
            int4 d4 = *(const int4*)(ei + E + e);
#define H2(S, D) if ((unsigned)(S) < (unsigned)n_nodes && (unsigned)(D) < (unsigned)n_nodes) { \
                atomicAdd(&hd[(D) >> CBSH], 1); atomicAdd(&hs[(S) >> CBSH], 1); }
            H2(s4.x, d4.x) H2(s4.y, d4.y) H2(s4.z, d4.z) H2(s4.w, d4.w)
#undef H2
        } else if (e < end) {
            for (int q = e; q < end; ++q) {
                int s = ei[q], d = ei[E + q];
                if ((unsigned)s >= (unsigned)n_nodes || (unsigned)d >= (unsigned)n_nodes)
                    continue;
                atomicAdd(&hd[d >> CBSH], 1);
                atomicAdd(&hs[s >> CBSH], 1);
            }
        }
    }
    __syncthreads();
    for (int i = threadIdx.x; i < nbuck; i += 256) {
        g_part2[i * NBLK + blockIdx.x] = hd[i];
        g_part2[(nbuck + i) * NBLK + blockIdx.x] = hs[i];
    }
    if (blockIdx.x == 0 && threadIdx.x == 0)
        g_part2[2 * nbuck * NBLK] = 0;        // scan sentinel
}

// --- exclusive scan over g_part2[0..n): scan1 (per-tile) + scan2 (tile sums).
// No scan3: consumers use scanned(). n ~ 400K -> 196 tiles. ---
__global__ __launch_bounds__(256) void scan1_kernel(int n) {
    __shared__ int sh[256];
    int tid = threadIdx.x;
    int base = blockIdx.x * SCAN_TILE + tid * 8;
    int v[8];
#pragma unroll
    for (int i = 0; i < 8; ++i) v[i] = (base + i < n) ? g_part2[base + i] : 0;
    int tsum = 0;
#pragma unroll
    for (int i = 0; i < 8; ++i) tsum += v[i];
    sh[tid] = tsum;
    __syncthreads();
    for (int off = 1; off < 256; off <<= 1) {
        int t = (tid >= off) ? sh[tid - off] : 0;
        __syncthreads();
        sh[tid] += t;
        __syncthreads();
    }
    if (tid == 255) g_blk[blockIdx.x] = sh[255];
    int run = sh[tid] - tsum;   // exclusive offset within tile
#pragma unroll
    for (int i = 0; i < 8; ++i) {
        if (base + i < n) g_part2[base + i] = run;
        run += v[i];
    }
}

__global__ __launch_bounds__(256) void scan2_kernel(int nb) {   // nb <= 1024
    __shared__ int sh[256];
    int tid = threadIdx.x;
    int base = tid * 4;
    int v[4];
#pragma unroll
    for (int i = 0; i < 4; ++i) v[i] = (base + i < nb) ? g_blk[base + i] : 0;
    int tsum = v[0] + v[1] + v[2] + v[3];
    sh[tid] = tsum;
    __syncthreads();
    for (int off = 1; off < 256; off <<= 1) {
        int t = (tid >= off) ? sh[tid - off] : 0;
        __syncthreads();
        sh[tid] += t;
        __syncthreads();
    }
    int run = sh[tid] - tsum;
#pragma unroll
    for (int i = 0; i < 4; ++i) {
        if (base + i < nb) g_blk[base + i] = run;
        run += v[i];
    }
}

// Two phases (dst records into g_rec, src records into g_srec). Per phase:
// counts/bases from the scanned matrix (via scanned()), 512-wide LDS
// Hillis-Steele for local run bases, cursor-scatter into staged LDS +
// per-record global position, then coalesced burst write-out.
__global__ __launch_bounds__(256) void scatter_burst_kernel(const int* __restrict__ ei,
                                                            const float* __restrict__ w,
                                                            int E, int n_nodes, int nbuck,
                                                            int per_blk) {
    __shared__ int   cnt[512];
    __shared__ int   sc[512];
    __shared__ int   gb[MAX_NB];
    __shared__ int   cur[MAX_NB];
    __shared__ uint2 staged[PERBLK];
    __shared__ int   gpos[PERBLK];
    int tid = threadIdx.x;
    int blk = blockIdx.x;
    int start = blk * per_blk;
    int end = start + per_blk;
    if (end > E) end = E;

    for (int phase = 0; phase < 2; ++phase) {
        cnt[tid] = 0; cnt[tid + 256] = 0;
        __syncthreads();
        for (int i = tid; i < nbuck; i += 256) {
            int flat = (phase * nbuck + i) * NBLK + blk;
            int g0 = scanned(flat);
            int g1 = scanned(flat + 1);            // flat successor = run end
            gb[i] = g0 - phase * E;                // src space is [E,2E)
            cnt[i] = g1 - g0;
        }
        __syncthreads();
        sc[tid] = cnt[tid]; sc[tid + 256] = cnt[tid + 256];
        __syncthreads();
        for (int off = 1; off < 512; off <<= 1) {  // inclusive scan, 512 wide
            int v0 = (tid >= off) ? sc[tid - off] : 0;
            int v1 = sc[tid + 256 - off];          // tid+256 >= off always
            __syncthreads();
            sc[tid] += v0; sc[tid + 256] += v1;
            __syncthreads();
        }
        for (int i = tid; i < nbuck; i += 256) cur[i] = sc[i] - cnt[i];
        __syncthreads();
#define SB1(S, D, W)                                                            \
        {   int s = (S), d = (D);                                               \
            if ((unsigned)s < (unsigned)n_nodes && (unsigned)d < (unsigned)n_nodes) { \
                int key = phase ? s : d;                                        \
                int bin = key >> CBSH;                                          \
                float w0 = (s == d) ? 0.f : (W);   /* self-loops: w=0 */        \
                unsigned pay = phase ? (unsigned)(s & (CB - 1))                 \
                    : (((unsigned)s << CBSH) | (unsigned)(d & (CB - 1)));       \
                int p = atomicAdd(&cur[bin], 1);   /* LDS cursor */             \
                staged[p] = make_uint2(pay, __float_as_uint(w0));               \
                gpos[p] = gb[bin] + (p - (sc[bin] - cnt[bin]));                 \
            } }
        for (int base = start; base < end; base += 1024) {
            int e = base + tid * 4;
            if (e + 4 <= end) {
                iv4 s4 = nt_i4(ei + e);
                iv4 d4 = nt_i4(ei + E + e);
                fv4 w4 = nt_f4(w + e);
                SB1(s4[0], d4[0], w4[0]) SB1(s4[1], d4[1], w4[1])
                SB1(s4[2], d4[2], w4[2]) SB1(s4[3], d4[3], w4[3])
            } else if (e < end) {
                for (int q = e; q < end; ++q) SB1(ei[q], ei[E + q], w[q])
            }
        }
#undef SB1
        __syncthreads();
        int tot = sc[511];                         // valid records in this chunk
        if (phase == 0) {
            for (int t = tid; t < tot; t += 256) g_rec[gpos[t]] = staged[t];
        } else {
            for (int t = tid; t < tot; t += 256) g_srec[gpos[t]] = staged[t];
        }
        __syncthreads();
    }
}

// One block per src bucket (256 nodes), 1024 THREADS (16 waves): was 256 thr
// x 391 blocks = 19% occupancy, latency-starved. LDS f32 accumulate w per
// local node, then write dinv = rsqrt(deg). No global atomics.
__global__ __launch_bounds__(1024) void deg_sum_kernel(int E, int n_nodes, int nbuck) {
    __shared__ float ldeg[CB];
    int b = blockIdx.x;
    int rs = scanned((nbuck + b) * NBLK) - E;
    int re = scanned((nbuck + b + 1) * NBLK) - E;   // b==nbuck-1 hits sentinel (2E)
    if (threadIdx.x < CB) ldeg[threadIdx.x] = 0.f;
    __syncthreads();
    for (int i = rs + threadIdx.x; i < re; i += 1024) {
        uint2 r = g_srec[i];
        atomicAdd(&ldeg[r.x], __uint_as_float(r.y));   // LDS atomic
    }
    __syncthreads();
    if (threadIdx.x < CB) {
        int node = (b << CBSH) + threadIdx.x;
        if (node < n_nodes) {
            float dg = ldeg[threadIdx.x];
            g_deg[node] = (dg > 0.f) ? rsqrtf(dg) : 0.f;
        }
    }
}

// One block per dst bucket (256 nodes, ~4096 records), 1024 THREADS (16 waves;
// was 19% occupancy). Count local nodes (LDS, 4x parallel), 4-wave hierarchical
// exclusive scan on the first 256 threads -> absolute g_row, then reorder
// records into per-node CSR (g_src2/g_nrm2), computing nrm on the fly.
__global__ __launch_bounds__(1024) void fine_sort_kernel(int E, int n_nodes, int nbuck) {
    __shared__ int cnt[CB];
    __shared__ int cur[CB];
    __shared__ float dv[CB];
    __shared__ int wsum[4];
    int b = blockIdx.x;
    int rs = scanned(b * NBLK);
    int re = scanned((b + 1) * NBLK);   // b==nbuck-1 hits first src bin (= E)
    if (threadIdx.x < CB) {
        int tid = threadIdx.x;
        cnt[tid] = 0;
        int node = (b << CBSH) + tid;
        dv[tid] = (node < n_nodes) ? g_deg[node] : 0.f;
    }
    __syncthreads();
    for (int i = rs + threadIdx.x; i < re; i += 1024)
        atomicAdd(&cnt[g_rec[i].x & (CB - 1)], 1);
    __syncthreads();
    if (threadIdx.x < CB) {             // first 4 waves: hierarchical scan
        int tid = threadIdx.x;
        int lane = tid & 63;
        int wave = tid >> 6;
        int v = cnt[tid];
        int inc = v;
#pragma unroll
        for (int off = 1; off < 64; off <<= 1) {
            int t = __shfl_up(inc, off, 64);
            if (lane >= off) inc += t;
        }
        if (lane == 63) wsum[wave] = inc;
        __syncthreads();
        int wo = 0;
#pragma unroll
        for (int ww = 0; ww < 4; ++ww) wo += (ww < wave) ? wsum[ww] : 0;
        int start = rs + wo + (inc - v);   // exclusive
        cur[tid] = start;
        int node = (b << CBSH) + tid;
        if (node < n_nodes) g_row[node] = start;
    } else {
        __syncthreads();                // match the scan's internal barrier
    }
    if (b == nbuck - 1 && threadIdx.x == 0) g_row[n_nodes] = re;
    __syncthreads();
    for (int i = rs + threadIdx.x; i < re; i += 1024) {
        uint2 r = g_rec[i];
        int s = (int)(r.x >> CBSH);
        int loc = r.x & (CB - 1);
        float nrm = -g_deg[s] * __uint_as_float(r.y) * dv[loc];
        int pos = atomicAdd(&cur[loc], 1);   // LDS atomic
        g_src2[pos] = s;
        g_nrm2[pos] = nrm;
    }
}

// Half-wave (32 lanes = 32 features) per node, REGISTER accumulators (dual),
// CSR stream nt, 8-deep unroll; 12.5k blocks -> max wave concurrency.
__global__ __launch_bounds__(256) void gather_kernel(const float* __restrict__ x,
                                                     int n_nodes) {
    int t = blockIdx.x * blockDim.x + threadIdx.x;
    int node = t >> 5;
    int f = t & 31;
    if (node >= n_nodes) return;
    int i = g_row[node];
    int end = g_row[node + 1];
    float acc = 0.f, accB = 0.f;
    while (i < end && (i & 3)) {           // peel to 16B alignment
        acc += g_nrm2[i] * x[g_src2[i] * FDIM + f];
        ++i;
    }
    for (; i + 8 <= end; i += 8) {
        iv4 sa = nt_i4(g_src2 + i);
        iv4 sb = nt_i4(g_src2 + i + 4);
        fv4 na = nt_f4(g_nrm2 + i);
        fv4 nb = nt_f4(g_nrm2 + i + 4);
        float xa0 = x[sa[0] * FDIM + f], xa1 = x[sa[1] * FDIM + f];
        float xa2 = x[sa[2] * FDIM + f], xa3 = x[sa[3] * FDIM + f];
        float xb0 = x[sb[0] * FDIM + f], xb1 = x[sb[1] * FDIM + f];
        float xb2 = x[sb[2] * FDIM + f], xb3 = x[sb[3] * FDIM + f];
        acc  += na[0] * xa0 + na[1] * xa1 + na[2] * xa2 + na[3] * xa3;
        accB += nb[0] * xb0 + nb[1] * xb1 + nb[2] * xb2 + nb[3] * xb3;
    }
    for (; i + 4 <= end; i += 4) {
        iv4 s4 = nt_i4(g_src2 + i);
        fv4 n4 = nt_f4(g_nrm2 + i);
        acc += n4[0] * x[s4[0] * FDIM + f] + n4[1] * x[s4[1] * FDIM + f]
             + n4[2] * x[s4[2] * FDIM + f] + n4[3] * x[s4[3] * FDIM + f];
    }
    for (; i < end; ++i) acc += g_nrm2[i] * x[g_src2[i] * FDIM + f];
    g_tx1[node * FDIM + f] = acc + accB;
}

// 64 nodes per 256-thread block. Thread (grp, j) accumulates output feature j
// of gates i,c,o for 8 nodes. k processed in chunks of 4: x/t read as float4
// broadcasts (b128, conflict-free), weights b32 coalesced.
__global__ __launch_bounds__(256, 4) void gates64_kernel(
    const float* __restrict__ x,
    const float* __restrict__ Wx, const float* __restrict__ bx,
    const float* __restrict__ bh, const float* __restrict__ wc,
    const float* __restrict__ bg, const float* __restrict__ lin_w,
    const float* __restrict__ lin_b, float* __restrict__ out, int n_nodes) {
    __shared__ float Ws[3 * 2048];      // gates {i,c,o} x K=2 x 32x32 = 24 KB
    __shared__ float xs[GNB * FDIM];    // 8 KB
    __shared__ float ts[GNB * FDIM];    // 8 KB

    for (int idx = threadIdx.x; idx < 512; idx += 256) {
        *(float4*)&Ws[idx * 4]        = *(const float4*)&Wx[0 * 2048 + idx * 4];
        *(float4*)&Ws[2048 + idx * 4] = *(const float4*)&Wx[2 * 2048 + idx * 4];
        *(float4*)&Ws[4096 + idx * 4] = *(const float4*)&Wx[3 * 2048 + idx * 4];
    }
    int node0 = blockIdx.x * GNB;
    for (int t = threadIdx.x; t < GNB * FDIM / 4; t += 256) {
        int q = t * 4;
        int n = node0 + (q >> 5);
        float4 xv = make_float4(0.f, 0.f, 0.f, 0.f);
        float4 tv = make_float4(0.f, 0.f, 0.f, 0.f);
        if (n < n_nodes) {
            xv = *(const float4*)&x[n * FDIM + (q & 31)];
            tv = *(const float4*)&g_tx1[n * FDIM + (q & 31)];
        }
        *(float4*)&xs[q] = xv;
        *(float4*)&ts[q] = tv;
    }
    __syncthreads();

    int j   = threadIdx.x & 31;
    int grp = threadIdx.x >> 5;         // 0..7, handles nodes grp*8 .. grp*8+7

    float ai0=0.f,ai1=0.f,ai2=0.f,ai3=0.f,ai4=0.f,ai5=0.f,ai6=0.f,ai7=0.f;
    float ac0=0.f,ac1=0.f,ac2=0.f,ac3=0.f,ac4=0.f,ac5=0.f,ac6=0.f,ac7=0.f;
    float ao0=0.f,ao1=0.f,ao2=0.f,ao3=0.f,ao4=0.f,ao5=0.f,ao6=0.f,ao7=0.f;
    const float* xr = &xs[(grp * 8) * FDIM];
    const float* tr = &ts[(grp * 8) * FDIM];
    for (int k4 = 0; k4 < 32; k4 += 4) {
        float4 xv0 = *(const float4*)(xr + 0 * FDIM + k4);
        float4 xv1 = *(const float4*)(xr + 1 * FDIM + k4);
        float4 xv2 = *(const float4*)(xr + 2 * FDIM + k4);
        float4 xv3 = *(const float4*)(xr + 3 * FDIM + k4);
        float4 xv4 = *(const float4*)(xr + 4 * FDIM + k4);
        float4 xv5 = *(const float4*)(xr + 5 * FDIM + k4);
        float4 xv6 = *(const float4*)(xr + 6 * FDIM + k4);
        float4 xv7 = *(const float4*)(xr + 7 * FDIM + k4);
        float4 tv0 = *(const float4*)(tr + 0 * FDIM + k4);
        float4 tv1 = *(const float4*)(tr + 1 * FDIM + k4);
        float4 tv2 = *(const float4*)(tr + 2 * FDIM + k4);
        float4 tv3 = *(const float4*)(tr + 3 * FDIM + k4);
        float4 tv4 = *(const float4*)(tr + 4 * FDIM + k4);
        float4 tv5 = *(const float4*)(tr + 5 * FDIM + k4);
        float4 tv6 = *(const float4*)(tr + 6 * FDIM + k4);
        float4 tv7 = *(const float4*)(tr + 7 * FDIM + k4);
#define KSTEP(kc, COMP)                                        \
        {   int o0 = (k4 + kc) * 32 + j;                       \
            float wi0 = Ws[o0],        wi1 = Ws[1024 + o0];    \
            float wg0 = Ws[2048 + o0], wg1 = Ws[3072 + o0];    \
            float wo0 = Ws[4096 + o0], wo1 = Ws[5120 + o0];    \
            ai0 += xv0.COMP * wi0 + tv0.COMP * wi1;            \
            ac0 += xv0.COMP * wg0 + tv0.COMP * wg1;            \
            ao0 += xv0.COMP * wo0 + tv0.COMP * wo1;            \
            ai1 += xv1.COMP * wi0 + tv1.COMP * wi1;            \
            ac1 += xv1.COMP * wg0 + tv1.COMP * wg1;            \
            ao1 += xv1.COMP * wo0 + tv1.COMP * wo1;            \
            ai2 += xv2.COMP * wi0 + tv2.COMP * wi1;            \
            ac2 += xv2.COMP * wg0 + tv2.COMP * wg1;            \
            ao2 += xv2.COMP * wo0 + tv2.COMP * wo1;            \
            ai3 += xv3.COMP * wi0 + tv3.COMP * wi1;            \
            ac3 += xv3.COMP * wg0 + tv3.COMP * wg1;            \
            ao3 += xv3.COMP * wo0 + tv3.COMP * wo1;            \
            ai4 += xv4.COMP * wi0 + tv4.COMP * wi1;            \
            ac4 += xv4.COMP * wg0 + tv4.COMP * wg1;            \
            ao4 += xv4.COMP * wo0 + tv4.COMP * wo1;            \
            ai5 += xv5.COMP * wi0 + tv5.COMP * wi1;            \
            ac5 += xv5.COMP * wg0 + tv5.COMP * wg1;            \
            ao5 += xv5.COMP * wo0 + tv5.COMP * wo1;            \
            ai6 += xv6.COMP * wi0 + tv6.COMP * wi1;            \
            ac6 += xv6.COMP * wg0 + tv6.COMP * wg1;            \
            ao6 += xv6.COMP * wo0 + tv6.COMP * wo1;            \
            ai7 += xv7.COMP * wi0 + tv7.COMP * wi1;            \
            ac7 += xv7.COMP * wg0 + tv7.COMP * wg1;            \
            ao7 += xv7.COMP * wo0 + tv7.COMP * wo1;            \
        }
        KSTEP(0, x) KSTEP(1, y) KSTEP(2, z) KSTEP(3, w)
#undef KSTEP
    }

    float bi = bx[0 * 32 + j] + bh[0 * 32 + j] + bg[0 * 32 + j];
    float bc = bx[2 * 32 + j] + bh[2 * 32 + j] + bg[2 * 32 + j];
    float bo = bx[3 * 32 + j] + bh[3 * 32 + j] + bg[3 * 32 + j];
    float wcp = wc[2 * 32 + j];
    float lwj = lin_w[j];
    float lb0 = lin_b[0];

#define GOUT(m, AI, AC, AO)                                            \
    {   int n = node0 + grp * 8 + m;                                   \
        float I = 1.f / (1.f + __expf(-(AI + bi)));                    \
        float T = tanhf(AC + bc);                                      \
        float C = I * T;                                               \
        float O = 1.f / (1.f + __expf(-(AO + bo + wcp * C)));          \
        float H = O * tanhf(C);                                        \
        float r = fmaxf(H, 0.f) * lwj;                                 \
        _Pragma("unroll")                                              \
        for (int mm = 16; mm > 0; mm >>= 1) r += __shfl_xor(r, mm, 32);\
        if (j == 0 && n < n_nodes) out[n] = r + lb0; }
    GOUT(0, ai0, ac0, ao0) GOUT(1, ai1, ac1, ao1)
    GOUT(2, ai2, ac2, ao2) GOUT(3, ai3, ac3, ao3)
    GOUT(4, ai4, ac4, ao4) GOUT(5, ai5, ac5, ao5)
    GOUT(6, ai6, ac6, ao6) GOUT(7, ai7, ac7, ao7)
#undef GOUT
}

extern "C" void kernel_launch(void* const* d_in, const int* in_sizes, int n_in,
                              void* d_out, int out_size, void* d_ws, size_t ws_size,
                              hipStream_t stream) {
    const float* x     = (const float*)d_in[0];
    const int*   ei    = (const int*)d_in[1];      // int32 on device
    const float* w     = (const float*)d_in[2];
    const float* Wx    = (const float*)d_in[3];
    const float* bx    = (const float*)d_in[4];
    // d_in[5] = Wh: unused (H=0)
    const float* bh    = (const float*)d_in[6];
    const float* wc    = (const float*)d_in[7];
    const float* bg    = (const float*)d_in[8];
    const float* lin_w = (const float*)d_in[9];
    const float* lin_b = (const float*)d_in[10];
    float*       out   = (float*)d_out;

    int n_nodes = in_sizes[0] / FDIM;
    if (n_nodes > MAX_N) n_nodes = MAX_N;
    int E = in_sizes[2];
    if (E > MAX_E) E = MAX_E;

    int nbuck   = (n_nodes + CB - 1) >> CBSH;            // 391 for N=100k
    int per_blk = (((E + NBLK - 1) / NBLK) + 3) & ~3;    // 3128, x4-aligned ranges
    int n_scan  = 2 * nbuck * NBLK + 1;                  // 400385
    int nb_scan = (n_scan + SCAN_TILE - 1) / SCAN_TILE;  // 196 (<= 1024 for scan2)

    hist2_kernel<<<NBLK, 256, 0, stream>>>(ei, E, n_nodes, nbuck, per_blk);
    scan1_kernel<<<nb_scan, 256, 0, stream>>>(n_scan);
    scan2_kernel<<<1, 256, 0, stream>>>(nb_scan);
    scatter_burst_kernel<<<NBLK, 256, 0, stream>>>(ei, w, E, n_nodes, nbuck, per_blk);
    deg_sum_kernel<<<nbuck, 1024, 0, stream>>>(E, n_nodes, nbuck);
    fine_sort_kernel<<<nbuck, 1024, 0, stream>>>(E, n_nodes, nbuck);
    {
        long long tot = (long long)n_nodes * 32;
        gather_kernel<<<(int)((tot + 255) / 256), 256, 0, stream>>>(x, n_nodes);
    }
    gates64_kernel<<<(n_nodes + GNB - 1) / GNB, 256, 0, stream>>>(
        x, Wx, bx, bh, wc, bg, lin_w, lin_b, out, n_nodes);
}